// Round 9
// baseline (487.323 us; speedup 1.0000x reference)
//
#include <hip/hip_runtime.h>

// Problem constants (fixed by setup_inputs)
#define M_DIM 8192      // 4*2048
#define N_DIM 4096      // out_f
#define K_DIM 4096      // in_f
#define GROUPS_PER_ROW 128
#define NT (K_DIM / 64) // 64 K-tiles of BK=64

typedef short bf16x8 __attribute__((ext_vector_type(8)));
typedef float f32x4  __attribute__((ext_vector_type(4)));
typedef unsigned short u16x8 __attribute__((ext_vector_type(8)));

__device__ __forceinline__ unsigned short f2bf(float f) {
    unsigned int u = __float_as_uint(f);
    u += 0x7fffu + ((u >> 16) & 1u);   // round-to-nearest-even
    return (unsigned short)(u >> 16);
}

typedef const __attribute__((address_space(1))) void gvoid_t;
typedef __attribute__((address_space(3))) void lvoid_t;
__device__ __forceinline__ void gload_lds16(const void* g, void* l) {
    __builtin_amdgcn_global_load_lds((gvoid_t*)g, (lvoid_t*)l, 16, 0, 0);
}

// ---------- pass 1: dequantize weight -> bf16 [N][K] ----------
__global__ __launch_bounds__(256) void dequant_kernel(
        const float* __restrict__ w, const float* __restrict__ value,
        const float* __restrict__ mins, const float* __restrict__ maxs,
        unsigned short* __restrict__ wq) {
    int g = blockIdx.x * 256 + threadIdx.x;
    const float4* wp = reinterpret_cast<const float4*>(w + (size_t)g * 32);
    const float4* vp = reinterpret_cast<const float4*>(value + (size_t)g * 32);
    float4 wv[8], vv[8];
    #pragma unroll
    for (int j = 0; j < 8; j++) { wv[j] = wp[j]; vv[j] = vp[j]; }
    float mn = wv[0].x, mx = wv[0].x;
    #pragma unroll
    for (int j = 0; j < 8; j++) {
        mn = fminf(mn, fminf(fminf(wv[j].x, wv[j].y), fminf(wv[j].z, wv[j].w)));
        mx = fmaxf(mx, fmaxf(fmaxf(wv[j].x, wv[j].y), fmaxf(wv[j].z, wv[j].w)));
    }
    float w_min = mn * mins[g];
    float w_max = mx * maxs[g];
    float scale = fmaxf((w_max - w_min) * (1.0f / 255.0f), 1e-8f);
    float zp    = -w_min / scale;
    float rs    = 1.0f / scale;
    unsigned short ob[32];
    #pragma unroll
    for (int j = 0; j < 8; j++) {
        const float* wf = &wv[j].x;
        const float* vf = &vv[j].x;
        #pragma unroll
        for (int c = 0; c < 4; c++) {
            float ws_ = wf[c] * rs + zp + vf[c];
            float q   = fminf(fmaxf(rintf(ws_), 0.0f), 255.0f);
            ob[j * 4 + c] = f2bf(scale * (q - zp));
        }
    }
    u16x8* op = reinterpret_cast<u16x8*>(wq + (size_t)g * 32);
    #pragma unroll
    for (int j = 0; j < 4; j++) {
        u16x8 v;
        #pragma unroll
        for (int c = 0; c < 8; c++) v[c] = ob[j * 8 + c];
        op[j] = v;
    }
}

// ---------- pass 2: x f32 -> bf16 ----------
__global__ __launch_bounds__(256) void xconv_kernel(
        const float* __restrict__ x, unsigned short* __restrict__ xb) {
    int t = blockIdx.x * 256 + threadIdx.x;
    const float4* xp = reinterpret_cast<const float4*>(x) + (size_t)t * 2;
    float4 a = xp[0], b = xp[1];
    u16x8 v;
    v[0] = f2bf(a.x); v[1] = f2bf(a.y); v[2] = f2bf(a.z); v[3] = f2bf(a.w);
    v[4] = f2bf(b.x); v[5] = f2bf(b.y); v[6] = f2bf(b.z); v[7] = f2bf(b.w);
    reinterpret_cast<u16x8*>(xb)[t] = v;
}

// ---------- pass 3: 256x256 8-wave GEMM-BT, A via LDS, B DIRECT FROM GLOBAL ----
// C[m][n] = sum_k A[m][k]*B[n][k] + bias[n]   (16x16x32 MFMA, round-4 layouts)
// Round-9 design: B fragments are read exactly once per wave -> no LDS value in
// staging them. B loads go global->VGPR (L2-resident: XCD map gives each XCD 2
// B panels = 4MB). LDS holds only A (dbuf 2x32KB): LDS pipe/tile drops
// 256KB -> 160KB, below the MFMA floor -> matrix pipe becomes the only floor.
// A staging goes to the buffer NOT read this tile (race-free by construction).
__global__ __launch_bounds__(512, 2) void gemm_kernel(
        const unsigned short* __restrict__ A, const unsigned short* __restrict__ B,
        const float* __restrict__ bias, float* __restrict__ C) {
    __shared__ __align__(128) char lds[65536];   // A only: 2 buffers x 32KB

    const int tid  = threadIdx.x;
    const int lane = tid & 63;
    const int w    = tid >> 6;          // 0..7
    const int wr   = w >> 2;            // 0..1 (M split: 128 rows)
    const int wc   = w & 3;             // 0..3 (N split: 64 cols)
    const int l15  = lane & 15, lk = lane >> 4;

    // XCD map (dispatch round-robins bid across 8 XCDs): each XCD owns
    // bn in {2x, 2x+1} -> B working set 2 panels = 4MB, fits its private L2.
    const int bid = blockIdx.x;
    const int bn  = (bid & 7) * 2 + ((bid >> 3) & 1);   // 0..15
    const int bm  = bid >> 4;                            // 0..31

    // A ds_read base (round-4 verified): swizzle bit9->bit5 folds per-thread
    const int swb   = ((l15 >> 3) & 1) << 5;
    const int rbyte = ((l15 * 64 + lk * 16) ^ swb);
    const int abase = wr * 16384 + rbyte;   // [half(wr)][2 kk][128 rows][64B]

    // A staging: linear 16B chunks; source inverse-swizzled (involution)
    const int c0  = tid * 16;
    const int c1  = 8192 + tid * 16;
    const int lb0 = c0 ^ (((c0 >> 9) & 1) << 5);
    const int lb1 = c1 ^ (((c1 >> 9) & 1) << 5);
    const int so0 = ((lb0 >> 6) & 127) * (K_DIM * 2) + (lb0 >> 13) * 64 + (lb0 & 63);
    const int so1 = ((lb1 >> 6) & 127) * (K_DIM * 2) + (lb1 >> 13) * 64 + (lb1 & 63);

    const char* srcA0 = (const char*)A + (size_t)(bm * 256 +   0) * (K_DIM * 2);
    const char* srcA1 = (const char*)A + (size_t)(bm * 256 + 128) * (K_DIM * 2);

    char* ldsc = (char*)lds;
    auto STAGE = [&](const char* src, int tt, int regionOff) {
        gload_lds16(src + (size_t)tt * 128 + so0, ldsc + regionOff + c0);
        gload_lds16(src + (size_t)tt * 128 + so1, ldsc + regionOff + c1);
    };

    // B global per-lane base: row = bn*256 + wc*64 + ni*16 + l15, k = t*64+kk*32+lk*8
    const unsigned short* bG = B + (size_t)(bn * 256 + wc * 64 + l15) * K_DIM + lk * 8;

    f32x4 acc[8][4] = {};
    bf16x8 bf_[4][2];

    // prologue: stage A tile0 -> buf0
    STAGE(srcA0, 0, 0);
    STAGE(srcA1, 0, 16384);
    asm volatile("s_waitcnt vmcnt(0)" ::: "memory");
    __builtin_amdgcn_s_barrier();
    __builtin_amdgcn_sched_barrier(0);

    #pragma unroll 2
    for (int t = 0; t < NT; ++t) {
        const int bo  = (t & 1) << 15;     // 0 / 32768
        const int bo2 = bo ^ 32768;

        // B fragments for this tile: 8 global 16B loads (L2-hot)
        #pragma unroll
        for (int ni = 0; ni < 4; ++ni)
            #pragma unroll
            for (int kk = 0; kk < 2; ++kk)
                bf_[ni][kk] = *(const bf16x8*)(bG + (size_t)ni * 16 * K_DIM
                                               + t * 64 + kk * 32);
        // stage A half0 of t+1 into the buffer nobody reads this tile
        if (t + 1 < NT) STAGE(srcA0, t + 1, bo2);

        // mi-pairs 0,1 (rows 0..63 of this wave's half)
        #pragma unroll
        for (int p = 0; p < 2; ++p) {
            bf16x8 af[2][2];
            #pragma unroll
            for (int i = 0; i < 2; ++i)
                #pragma unroll
                for (int kk = 0; kk < 2; ++kk)
                    af[i][kk] = *(const bf16x8*)(ldsc + bo + abase
                                    + (p * 2 + i) * 1024 + kk * 8192);
            __builtin_amdgcn_s_setprio(1);
            #pragma unroll
            for (int i = 0; i < 2; ++i)
                #pragma unroll
                for (int ni = 0; ni < 4; ++ni)
                    #pragma unroll
                    for (int kk = 0; kk < 2; ++kk)
                        acc[p * 2 + i][ni] = __builtin_amdgcn_mfma_f32_16x16x32_bf16(
                            af[i][kk], bf_[ni][kk], acc[p * 2 + i][ni], 0, 0, 0);
            __builtin_amdgcn_s_setprio(0);
        }

        // stage A half1 of t+1; mid barrier keeps waves loosely in step
        if (t + 1 < NT) STAGE(srcA1, t + 1, bo2 + 16384);
        __builtin_amdgcn_s_barrier();
        __builtin_amdgcn_sched_barrier(0);

        // mi-pairs 2,3 (rows 64..127)
        #pragma unroll
        for (int p = 2; p < 4; ++p) {
            bf16x8 af[2][2];
            #pragma unroll
            for (int i = 0; i < 2; ++i)
                #pragma unroll
                for (int kk = 0; kk < 2; ++kk)
                    af[i][kk] = *(const bf16x8*)(ldsc + bo + abase
                                    + (p * 2 + i) * 1024 + kk * 8192);
            __builtin_amdgcn_s_setprio(1);
            #pragma unroll
            for (int i = 0; i < 2; ++i)
                #pragma unroll
                for (int ni = 0; ni < 4; ++ni)
                    #pragma unroll
                    for (int kk = 0; kk < 2; ++kk)
                        acc[p * 2 + i][ni] = __builtin_amdgcn_mfma_f32_16x16x32_bf16(
                            af[i][kk], bf_[ni][kk], acc[p * 2 + i][ni], 0, 0, 0);
            __builtin_amdgcn_s_setprio(0);
        }

        // tile end: drain A(t+1) stages (issued ~half a tile ago), one barrier
        asm volatile("s_waitcnt vmcnt(0)" ::: "memory");
        __builtin_amdgcn_s_barrier();
        __builtin_amdgcn_sched_barrier(0);
    }

    // epilogue: C/D layout col=lane&15, row=(lane>>4)*4+r (round-4 verified)
    float bv[4];
    #pragma unroll
    for (int ni = 0; ni < 4; ++ni)
        bv[ni] = bias[bn * 256 + wc * 64 + ni * 16 + l15];
    #pragma unroll
    for (int mi = 0; mi < 8; ++mi) {
        const int m0 = bm * 256 + wr * 128 + mi * 16 + lk * 4;
        #pragma unroll
        for (int ni = 0; ni < 4; ++ni) {
            const int n = bn * 256 + wc * 64 + ni * 16 + l15;
            #pragma unroll
            for (int r = 0; r < 4; ++r)
                C[(size_t)(m0 + r) * N_DIM + n] = acc[mi][ni][r] + bv[ni];
        }
    }
}

// ---------- fallback (ws too small): slow but correct ----------
__global__ __launch_bounds__(256) void fallback_gemm(
        const float* __restrict__ x, const float* __restrict__ w,
        const float* __restrict__ value, const float* __restrict__ mins,
        const float* __restrict__ maxs, const float* __restrict__ bias,
        float* __restrict__ out) {
    const int n = blockIdx.x;
    __shared__ float wrow[K_DIM];
    const int tid = threadIdx.x;
    if (tid < GROUPS_PER_ROW) {
        const int g = tid;
        const float* wp = w + (size_t)n * K_DIM + g * 32;
        const float* vp = value + (size_t)n * K_DIM + g * 32;
        float tw[32];
        float mn = 1e30f, mx = -1e30f;
        #pragma unroll
        for (int j = 0; j < 32; j++) {
            tw[j] = wp[j]; mn = fminf(mn, tw[j]); mx = fmaxf(mx, tw[j]);
        }
        float wmin = mn * mins[n * GROUPS_PER_ROW + g];
        float wmax = mx * maxs[n * GROUPS_PER_ROW + g];
        float scale = fmaxf((wmax - wmin) * (1.0f / 255.0f), 1e-8f);
        float zp = -wmin / scale;
        #pragma unroll
        for (int j = 0; j < 32; j++) {
            float ws_ = tw[j] / scale + zp + vp[j];
            float q = fminf(fmaxf(rintf(ws_), 0.0f), 255.0f);
            wrow[g * 32 + j] = scale * (q - zp);
        }
    }
    __syncthreads();
    const float bv = bias[n];
    for (int m = tid; m < M_DIM; m += 256) {
        const float4* xr = reinterpret_cast<const float4*>(x + (size_t)m * K_DIM);
        const float4* wr4 = reinterpret_cast<const float4*>(wrow);
        float s = 0.f;
        for (int k = 0; k < K_DIM / 4; k++) {
            float4 a = xr[k], b = wr4[k];
            s += a.x * b.x + a.y * b.y + a.z * b.z + a.w * b.w;
        }
        out[(size_t)m * N_DIM + n] = s + bv;
    }
}

extern "C" void kernel_launch(void* const* d_in, const int* in_sizes, int n_in,
                              void* d_out, int out_size, void* d_ws, size_t ws_size,
                              hipStream_t stream) {
    const float* x     = (const float*)d_in[0];
    const float* ow    = (const float*)d_in[1];
    const float* value = (const float*)d_in[2];
    const float* mins  = (const float*)d_in[3];
    const float* maxs  = (const float*)d_in[4];
    const float* bias  = (const float*)d_in[5];
    float* out = (float*)d_out;

    const size_t xb_bytes = (size_t)M_DIM * K_DIM * 2;
    const size_t wb_bytes = (size_t)N_DIM * K_DIM * 2;

    if (ws_size >= xb_bytes + wb_bytes) {
        unsigned short* xb = (unsigned short*)d_ws;
        unsigned short* wb = (unsigned short*)((char*)d_ws + xb_bytes);

        dequant_kernel<<<(N_DIM * GROUPS_PER_ROW) / 256, 256, 0, stream>>>(
            ow, value, mins, maxs, wb);
        xconv_kernel<<<(M_DIM * K_DIM / 8) / 256, 256, 0, stream>>>(x, xb);
        gemm_kernel<<<(M_DIM / 256) * (N_DIM / 256), 512, 0, stream>>>(
            xb, wb, bias, out);
    } else {
        fallback_gemm<<<N_DIM, 256, 0, stream>>>(x, ow, value, mins, maxs, bias, out);
    }
}

// Round 10
// 290.404 us; speedup vs baseline: 1.6781x; 1.6781x over previous
//
#include <hip/hip_runtime.h>

// Problem constants (fixed by setup_inputs)
#define M_DIM 8192      // 4*2048
#define N_DIM 4096      // out_f
#define K_DIM 4096      // in_f
#define GROUPS_PER_ROW 128
#define NT (K_DIM / 64) // 64 K-tiles of BK=64

typedef short bf16x8 __attribute__((ext_vector_type(8)));
typedef float f32x4  __attribute__((ext_vector_type(4)));
typedef unsigned short u16x8 __attribute__((ext_vector_type(8)));

__device__ __forceinline__ unsigned short f2bf(float f) {
    unsigned int u = __float_as_uint(f);
    u += 0x7fffu + ((u >> 16) & 1u);   // round-to-nearest-even
    return (unsigned short)(u >> 16);
}

typedef const __attribute__((address_space(1))) void gvoid_t;
typedef __attribute__((address_space(3))) void lvoid_t;
__device__ __forceinline__ void gload_lds16(const void* g, void* l) {
    __builtin_amdgcn_global_load_lds((gvoid_t*)g, (lvoid_t*)l, 16, 0, 0);
}

// ---------- pass 1: dequantize weight -> bf16 [N][K] ----------
__global__ __launch_bounds__(256) void dequant_kernel(
        const float* __restrict__ w, const float* __restrict__ value,
        const float* __restrict__ mins, const float* __restrict__ maxs,
        unsigned short* __restrict__ wq) {
    int g = blockIdx.x * 256 + threadIdx.x;
    const float4* wp = reinterpret_cast<const float4*>(w + (size_t)g * 32);
    const float4* vp = reinterpret_cast<const float4*>(value + (size_t)g * 32);
    float4 wv[8], vv[8];
    #pragma unroll
    for (int j = 0; j < 8; j++) { wv[j] = wp[j]; vv[j] = vp[j]; }
    float mn = wv[0].x, mx = wv[0].x;
    #pragma unroll
    for (int j = 0; j < 8; j++) {
        mn = fminf(mn, fminf(fminf(wv[j].x, wv[j].y), fminf(wv[j].z, wv[j].w)));
        mx = fmaxf(mx, fmaxf(fmaxf(wv[j].x, wv[j].y), fmaxf(wv[j].z, wv[j].w)));
    }
    float w_min = mn * mins[g];
    float w_max = mx * maxs[g];
    float scale = fmaxf((w_max - w_min) * (1.0f / 255.0f), 1e-8f);
    float zp    = -w_min / scale;
    float rs    = 1.0f / scale;
    unsigned short ob[32];
    #pragma unroll
    for (int j = 0; j < 8; j++) {
        const float* wf = &wv[j].x;
        const float* vf = &vv[j].x;
        #pragma unroll
        for (int c = 0; c < 4; c++) {
            float ws_ = wf[c] * rs + zp + vf[c];
            float q   = fminf(fmaxf(rintf(ws_), 0.0f), 255.0f);
            ob[j * 4 + c] = f2bf(scale * (q - zp));
        }
    }
    u16x8* op = reinterpret_cast<u16x8*>(wq + (size_t)g * 32);
    #pragma unroll
    for (int j = 0; j < 4; j++) {
        u16x8 v;
        #pragma unroll
        for (int c = 0; c < 8; c++) v[c] = ob[j * 8 + c];
        op[j] = v;
    }
}

// ---------- pass 2: x f32 -> bf16 ----------
__global__ __launch_bounds__(256) void xconv_kernel(
        const float* __restrict__ x, unsigned short* __restrict__ xb) {
    int t = blockIdx.x * 256 + threadIdx.x;
    const float4* xp = reinterpret_cast<const float4*>(x) + (size_t)t * 2;
    float4 a = xp[0], b = xp[1];
    u16x8 v;
    v[0] = f2bf(a.x); v[1] = f2bf(a.y); v[2] = f2bf(a.z); v[3] = f2bf(a.w);
    v[4] = f2bf(b.x); v[5] = f2bf(b.y); v[6] = f2bf(b.z); v[7] = f2bf(b.w);
    reinterpret_cast<u16x8*>(xb)[t] = v;
}

// ---------- pass 3: 256x256 8-wave 8-PHASE/2-K-TILE bf16 MFMA GEMM-BT + bias ----
// C[m][n] = sum_k A[m][k]*B[n][k] + bias[n]   (16x16x32 MFMA, round-4 verified
// layouts: LDS buf b at b*64KB; A [2 half][2 kk][128 rows][64B] at +0, B at +32KB;
// st_16x32 swizzle bit9->bit5 both sides; 0 bank conflicts measured.)
//
// Round-10 schedule: iteration = 2 K-tiles (even->buf0, odd->buf1), 8 phases,
// ONE half-tile staged per phase, placed >=1 phase after that region's last
// reader drained (per-phase lgkmcnt(0) before MFMA + end-of-phase barrier make
// this provably race-free). Region deaths: B halves after P2, A after P3.
//   P1: stage A_lo(t+1)->buf1   P5: stage A_lo(t+2)->buf0
//   P2: stage A_hi(t+1)->buf1   P6: stage A_hi(t+2)->buf0
//   P3: stage B_lo(t+2)->buf0   P7: stage B_lo(t+3)->buf1
//   P4: stage B_hi(t+2)->buf0   P8: stage B_hi(t+3)->buf1
// vmcnt(4) at P4/P8 only: drains exactly the next-read tile's 4 halves,
// leaves 2 half-tiles in flight. Every half-tile has 2-5 phases of slack.
__global__ __launch_bounds__(512, 2) void gemm_kernel(
        const unsigned short* __restrict__ A, const unsigned short* __restrict__ B,
        const float* __restrict__ bias, float* __restrict__ C) {
    __shared__ __align__(128) char lds[131072];

    const int tid  = threadIdx.x;
    const int lane = tid & 63;
    const int w    = tid >> 6;          // 0..7
    const int wr   = w >> 2;            // 0..1 (M split)
    const int wc   = w & 3;             // 0..3 (N split)
    const int l15  = lane & 15, lk = lane >> 4;

    // T1: bijective XCD swizzle (grid=512, 512%8==0)
    const int bid = blockIdx.x;
    const int swz = (bid & 7) * 64 + (bid >> 3);
    const int bm  = swz >> 4;           // 0..31
    const int bn  = swz & 15;           // 0..15

    // ds_read bases (swizzle bit9->bit5 folds to per-thread constant)
    const int swb   = ((l15 >> 3) & 1) << 5;
    const int rbyte = ((l15 * 64 + lk * 16) ^ swb);
    const int abase = wr * 16384 + rbyte;
    const int bbase = 32768 + (wc >> 1) * 16384 + (wc & 1) * 4096 + rbyte;

    // staging: linear 16B chunks; source inverse-swizzled (involution)
    const int c0  = tid * 16;
    const int c1  = 8192 + tid * 16;
    const int lb0 = c0 ^ (((c0 >> 9) & 1) << 5);
    const int lb1 = c1 ^ (((c1 >> 9) & 1) << 5);
    const int so0 = ((lb0 >> 6) & 127) * (K_DIM * 2) + (lb0 >> 13) * 64 + (lb0 & 63);
    const int so1 = ((lb1 >> 6) & 127) * (K_DIM * 2) + (lb1 >> 13) * 64 + (lb1 & 63);

    const char* srcA0 = (const char*)A + (size_t)(bm * 256 +   0) * (K_DIM * 2);
    const char* srcA1 = (const char*)A + (size_t)(bm * 256 + 128) * (K_DIM * 2);
    const char* srcB0 = (const char*)B + (size_t)(bn * 256 +   0) * (K_DIM * 2);
    const char* srcB1 = (const char*)B + (size_t)(bn * 256 + 128) * (K_DIM * 2);

    char* ldsc = (char*)lds;
    auto STAGE = [&](const char* src, int tt, int regionOff) {
        gload_lds16(src + (size_t)tt * 128 + so0, ldsc + regionOff + c0);
        gload_lds16(src + (size_t)tt * 128 + so1, ldsc + regionOff + c1);
    };

    f32x4 acc[8][4] = {};
    bf16x8 af[4][2], bfA[2][2], bfB[2][2];

    auto RD_AF = [&](int bufo, int half) {      // af <- A fragment block (mh)
        #pragma unroll
        for (int mi = 0; mi < 4; ++mi)
            #pragma unroll
            for (int kk = 0; kk < 2; ++kk)
                af[mi][kk] = *(const bf16x8*)(ldsc + bufo + abase + half * 4096
                                + mi * 1024 + kk * 8192);
    };
    auto RD_BF = [&](int bufo, bf16x8 (&bf)[2][2], int nb) {  // B frag pair
        #pragma unroll
        for (int j = 0; j < 2; ++j)
            #pragma unroll
            for (int kk = 0; kk < 2; ++kk)
                bf[j][kk] = *(const bf16x8*)(ldsc + bufo + bbase + (nb + j) * 1024
                                + kk * 8192);
    };
    auto MF = [&](bf16x8 (&bf)[2][2], int mo, int no) {       // 16-MFMA quadrant
        #pragma unroll
        for (int mi = 0; mi < 4; ++mi)
            #pragma unroll
            for (int j = 0; j < 2; ++j)
                #pragma unroll
                for (int kk = 0; kk < 2; ++kk)
                    acc[mo + mi][no + j] = __builtin_amdgcn_mfma_f32_16x16x32_bf16(
                        af[mi][kk], bf[j][kk], acc[mo + mi][no + j], 0, 0, 0);
    };

    #define LG0  do { asm volatile("s_waitcnt lgkmcnt(0)" ::: "memory"); \
                      __builtin_amdgcn_sched_barrier(0); } while (0)
    #define PRIO1 __builtin_amdgcn_s_setprio(1)
    #define PRIO0 __builtin_amdgcn_s_setprio(0)
    #define BAR  __builtin_amdgcn_s_barrier()

    // prologue: tile0 full -> buf0; tile1 B halves -> buf1  (12 loads)
    STAGE(srcA0, 0, 0);
    STAGE(srcA1, 0, 16384);
    STAGE(srcB0, 0, 32768);
    STAGE(srcB1, 0, 49152);
    STAGE(srcB0, 1, 65536 + 32768);
    STAGE(srcB1, 1, 65536 + 49152);
    asm volatile("s_waitcnt vmcnt(4)" ::: "memory");   // tile0's 8 landed
    BAR;
    __builtin_amdgcn_sched_barrier(0);

    for (int t = 0; t < NT; t += 2) {
        const bool g2 = (t + 2 < NT);

        // ======== tile t (buf0) ========
        // P1: reads af(mh0)+bfA; stage A_lo(t+1)->buf1; MFMA Q00
        RD_AF(0, 0); RD_BF(0, bfA, 0);
        STAGE(srcA0, t + 1, 65536 + 0);
        LG0; PRIO1; MF(bfA, 0, 0); PRIO0; BAR;

        // P2: reads bfB; stage A_hi(t+1)->buf1; MFMA Q01
        RD_BF(0, bfB, 2);
        STAGE(srcA1, t + 1, 65536 + 16384);
        LG0; PRIO1; MF(bfB, 0, 2); PRIO0; BAR;

        // P3: reads af(mh1); stage B_lo(t+2)->buf0; MFMA Q11
        RD_AF(0, 1);
        if (g2) STAGE(srcB0, t + 2, 32768);
        LG0; PRIO1; MF(bfB, 4, 2); PRIO0; BAR;

        // P4: stage B_hi(t+2)->buf0; MFMA Q10; counted vmcnt
        if (g2) STAGE(srcB1, t + 2, 49152);
        PRIO1; MF(bfA, 4, 0); PRIO0;
        if (g2) { asm volatile("s_waitcnt vmcnt(4)" ::: "memory"); }
        else    { asm volatile("s_waitcnt vmcnt(0)" ::: "memory"); }
        BAR;

        // ======== tile t+1 (buf1) ========
        // P5: reads af(mh0)+bfA; stage A_lo(t+2)->buf0; MFMA Q00
        RD_AF(65536, 0); RD_BF(65536, bfA, 0);
        if (g2) STAGE(srcA0, t + 2, 0);
        LG0; PRIO1; MF(bfA, 0, 0); PRIO0; BAR;

        // P6: reads bfB; stage A_hi(t+2)->buf0; MFMA Q01
        RD_BF(65536, bfB, 2);
        if (g2) STAGE(srcA1, t + 2, 16384);
        LG0; PRIO1; MF(bfB, 0, 2); PRIO0; BAR;

        // P7: reads af(mh1); stage B_lo(t+3)->buf1; MFMA Q11
        RD_AF(65536, 1);
        if (g2) STAGE(srcB0, t + 3, 65536 + 32768);
        LG0; PRIO1; MF(bfB, 4, 2); PRIO0; BAR;

        // P8: stage B_hi(t+3)->buf1; MFMA Q10; counted vmcnt
        if (g2) STAGE(srcB1, t + 3, 65536 + 49152);
        PRIO1; MF(bfA, 4, 0); PRIO0;
        if (g2) { asm volatile("s_waitcnt vmcnt(4)" ::: "memory"); }
        BAR;
    }

    #undef LG0
    #undef PRIO1
    #undef PRIO0
    #undef BAR

    // epilogue: C/D layout col=lane&15, row=(lane>>4)*4+r (round-4 verified)
    float bv[4];
    #pragma unroll
    for (int ni = 0; ni < 4; ++ni)
        bv[ni] = bias[bn * 256 + wc * 64 + ni * 16 + l15];
    #pragma unroll
    for (int mi = 0; mi < 8; ++mi) {
        const int m0 = bm * 256 + wr * 128 + mi * 16 + lk * 4;
        #pragma unroll
        for (int ni = 0; ni < 4; ++ni) {
            const int n = bn * 256 + wc * 64 + ni * 16 + l15;
            #pragma unroll
            for (int r = 0; r < 4; ++r)
                C[(size_t)(m0 + r) * N_DIM + n] = acc[mi][ni][r] + bv[ni];
        }
    }
}

// ---------- fallback (ws too small): slow but correct ----------
__global__ __launch_bounds__(256) void fallback_gemm(
        const float* __restrict__ x, const float* __restrict__ w,
        const float* __restrict__ value, const float* __restrict__ mins,
        const float* __restrict__ maxs, const float* __restrict__ bias,
        float* __restrict__ out) {
    const int n = blockIdx.x;
    __shared__ float wrow[K_DIM];
    const int tid = threadIdx.x;
    if (tid < GROUPS_PER_ROW) {
        const int g = tid;
        const float* wp = w + (size_t)n * K_DIM + g * 32;
        const float* vp = value + (size_t)n * K_DIM + g * 32;
        float tw[32];
        float mn = 1e30f, mx = -1e30f;
        #pragma unroll
        for (int j = 0; j < 32; j++) {
            tw[j] = wp[j]; mn = fminf(mn, tw[j]); mx = fmaxf(mx, tw[j]);
        }
        float wmin = mn * mins[n * GROUPS_PER_ROW + g];
        float wmax = mx * maxs[n * GROUPS_PER_ROW + g];
        float scale = fmaxf((wmax - wmin) * (1.0f / 255.0f), 1e-8f);
        float zp = -wmin / scale;
        #pragma unroll
        for (int j = 0; j < 32; j++) {
            float ws_ = tw[j] / scale + zp + vp[j];
            float q = fminf(fmaxf(rintf(ws_), 0.0f), 255.0f);
            wrow[g * 32 + j] = scale * (q - zp);
        }
    }
    __syncthreads();
    const float bv = bias[n];
    for (int m = tid; m < M_DIM; m += 256) {
        const float4* xr = reinterpret_cast<const float4*>(x + (size_t)m * K_DIM);
        const float4* wr4 = reinterpret_cast<const float4*>(wrow);
        float s = 0.f;
        for (int k = 0; k < K_DIM / 4; k++) {
            float4 a = xr[k], b = wr4[k];
            s += a.x * b.x + a.y * b.y + a.z * b.z + a.w * b.w;
        }
        out[(size_t)m * N_DIM + n] = s + bv;
    }
}

extern "C" void kernel_launch(void* const* d_in, const int* in_sizes, int n_in,
                              void* d_out, int out_size, void* d_ws, size_t ws_size,
                              hipStream_t stream) {
    const float* x     = (const float*)d_in[0];
    const float* ow    = (const float*)d_in[1];
    const float* value = (const float*)d_in[2];
    const float* mins  = (const float*)d_in[3];
    const float* maxs  = (const float*)d_in[4];
    const float* bias  = (const float*)d_in[5];
    float* out = (float*)d_out;

    const size_t xb_bytes = (size_t)M_DIM * K_DIM * 2;
    const size_t wb_bytes = (size_t)N_DIM * K_DIM * 2;

    if (ws_size >= xb_bytes + wb_bytes) {
        unsigned short* xb = (unsigned short*)d_ws;
        unsigned short* wb = (unsigned short*)((char*)d_ws + xb_bytes);

        dequant_kernel<<<(N_DIM * GROUPS_PER_ROW) / 256, 256, 0, stream>>>(
            ow, value, mins, maxs, wb);
        xconv_kernel<<<(M_DIM * K_DIM / 8) / 256, 256, 0, stream>>>(x, xb);
        gemm_kernel<<<(M_DIM / 256) * (N_DIM / 256), 512, 0, stream>>>(
            xb, wb, bias, out);
    } else {
        fallback_gemm<<<N_DIM, 256, 0, stream>>>(x, ow, value, mins, maxs, bias, out);
    }
}

// Round 11
// 289.617 us; speedup vs baseline: 1.6826x; 1.0027x over previous
//
#include <hip/hip_runtime.h>

// Problem constants (fixed by setup_inputs)
#define M_DIM 8192      // 4*2048
#define N_DIM 4096      // out_f
#define K_DIM 4096      // in_f
#define GROUPS_PER_ROW 128
#define NT (K_DIM / 64) // 64 K-tiles of BK=64

typedef short bf16x8 __attribute__((ext_vector_type(8)));
typedef float f32x4  __attribute__((ext_vector_type(4)));
typedef unsigned short u16x8 __attribute__((ext_vector_type(8)));

__device__ __forceinline__ unsigned short f2bf(float f) {
    unsigned int u = __float_as_uint(f);
    u += 0x7fffu + ((u >> 16) & 1u);   // round-to-nearest-even
    return (unsigned short)(u >> 16);
}

typedef const __attribute__((address_space(1))) void gvoid_t;
typedef __attribute__((address_space(3))) void lvoid_t;
__device__ __forceinline__ void gload_lds16(const void* g, void* l) {
    __builtin_amdgcn_global_load_lds((gvoid_t*)g, (lvoid_t*)l, 16, 0, 0);
}

// ---------- pass 1: dequantize weight -> bf16 [N][K] ----------
__global__ __launch_bounds__(256) void dequant_kernel(
        const float* __restrict__ w, const float* __restrict__ value,
        const float* __restrict__ mins, const float* __restrict__ maxs,
        unsigned short* __restrict__ wq) {
    int g = blockIdx.x * 256 + threadIdx.x;
    const float4* wp = reinterpret_cast<const float4*>(w + (size_t)g * 32);
    const float4* vp = reinterpret_cast<const float4*>(value + (size_t)g * 32);
    float4 wv[8], vv[8];
    #pragma unroll
    for (int j = 0; j < 8; j++) { wv[j] = wp[j]; vv[j] = vp[j]; }
    float mn = wv[0].x, mx = wv[0].x;
    #pragma unroll
    for (int j = 0; j < 8; j++) {
        mn = fminf(mn, fminf(fminf(wv[j].x, wv[j].y), fminf(wv[j].z, wv[j].w)));
        mx = fmaxf(mx, fmaxf(fmaxf(wv[j].x, wv[j].y), fmaxf(wv[j].z, wv[j].w)));
    }
    float w_min = mn * mins[g];
    float w_max = mx * maxs[g];
    float scale = fmaxf((w_max - w_min) * (1.0f / 255.0f), 1e-8f);
    float zp    = -w_min / scale;
    float rs    = 1.0f / scale;
    unsigned short ob[32];
    #pragma unroll
    for (int j = 0; j < 8; j++) {
        const float* wf = &wv[j].x;
        const float* vf = &vv[j].x;
        #pragma unroll
        for (int c = 0; c < 4; c++) {
            float ws_ = wf[c] * rs + zp + vf[c];
            float q   = fminf(fmaxf(rintf(ws_), 0.0f), 255.0f);
            ob[j * 4 + c] = f2bf(scale * (q - zp));
        }
    }
    u16x8* op = reinterpret_cast<u16x8*>(wq + (size_t)g * 32);
    #pragma unroll
    for (int j = 0; j < 4; j++) {
        u16x8 v;
        #pragma unroll
        for (int c = 0; c < 8; c++) v[c] = ob[j * 8 + c];
        op[j] = v;
    }
}

// ---------- pass 2: x f32 -> bf16 ----------
__global__ __launch_bounds__(256) void xconv_kernel(
        const float* __restrict__ x, unsigned short* __restrict__ xb) {
    int t = blockIdx.x * 256 + threadIdx.x;
    const float4* xp = reinterpret_cast<const float4*>(x) + (size_t)t * 2;
    float4 a = xp[0], b = xp[1];
    u16x8 v;
    v[0] = f2bf(a.x); v[1] = f2bf(a.y); v[2] = f2bf(a.z); v[3] = f2bf(a.w);
    v[4] = f2bf(b.x); v[5] = f2bf(b.y); v[6] = f2bf(b.z); v[7] = f2bf(b.w);
    reinterpret_cast<u16x8*>(xb)[t] = v;
}

// ---------- pass 3: 256x256 8-wave BALANCED-PHASE bf16 MFMA GEMM-BT + bias ----
// C[m][n] = sum_k A[m][k]*B[n][k] + bias[n]   (16x16x32 MFMA, round-4 verified
// layouts; st_16x32 swizzle bit9->bit5 both sides; 0 bank conflicts measured.)
//
// Round-11: per-phase ds_read balance 8,8,4,4 (was 12,4,8,0). Phases decompose
// over (m-half x k-half) instead of C-quadrants: every 16-MFMA cluster has a
// matched-or-smaller LDS service burst to hide. Per-accumulator add order is
// unchanged (kk0 then kk1) -> bit-identical result (absmax tripwire = 2.0).
// Stage map = round-10's provably race-free map (stage lands >=1 barrier after
// the region's last reader drained). vmcnt(4) at tile end only.
//   tile t (buf0):  P1 stage A_lo(t+1)->buf1, P2 A_hi(t+1)->buf1,
//                   P3 B_lo(t+2)->buf0,       P4 B_hi(t+2)->buf0  + vmcnt
//   tile t+1 (buf1):P5 A_lo(t+2)->buf0, P6 A_hi(t+2)->buf0,
//                   P7 B_lo(t+3)->buf1, P8 B_hi(t+3)->buf1        + vmcnt
__global__ __launch_bounds__(512, 2) void gemm_kernel(
        const unsigned short* __restrict__ A, const unsigned short* __restrict__ B,
        const float* __restrict__ bias, float* __restrict__ C) {
    __shared__ __align__(128) char lds[131072];

    const int tid  = threadIdx.x;
    const int lane = tid & 63;
    const int w    = tid >> 6;          // 0..7
    const int wr   = w >> 2;            // 0..1 (M split)
    const int wc   = w & 3;             // 0..3 (N split)
    const int l15  = lane & 15, lk = lane >> 4;

    // T1: bijective XCD swizzle (grid=512, 512%8==0)
    const int bid = blockIdx.x;
    const int swz = (bid & 7) * 64 + (bid >> 3);
    const int bm  = swz >> 4;           // 0..31
    const int bn  = swz & 15;           // 0..15

    // ds_read bases (swizzle bit9->bit5 folds to per-thread constant)
    const int swb   = ((l15 >> 3) & 1) << 5;
    const int rbyte = ((l15 * 64 + lk * 16) ^ swb);
    const int abase = wr * 16384 + rbyte;
    const int bbase = 32768 + (wc >> 1) * 16384 + (wc & 1) * 4096 + rbyte;

    // staging: linear 16B chunks; source inverse-swizzled (involution)
    const int c0  = tid * 16;
    const int c1  = 8192 + tid * 16;
    const int lb0 = c0 ^ (((c0 >> 9) & 1) << 5);
    const int lb1 = c1 ^ (((c1 >> 9) & 1) << 5);
    const int so0 = ((lb0 >> 6) & 127) * (K_DIM * 2) + (lb0 >> 13) * 64 + (lb0 & 63);
    const int so1 = ((lb1 >> 6) & 127) * (K_DIM * 2) + (lb1 >> 13) * 64 + (lb1 & 63);

    const char* srcA0 = (const char*)A + (size_t)(bm * 256 +   0) * (K_DIM * 2);
    const char* srcA1 = (const char*)A + (size_t)(bm * 256 + 128) * (K_DIM * 2);
    const char* srcB0 = (const char*)B + (size_t)(bn * 256 +   0) * (K_DIM * 2);
    const char* srcB1 = (const char*)B + (size_t)(bn * 256 + 128) * (K_DIM * 2);

    char* ldsc = (char*)lds;
    auto STAGE = [&](const char* src, int tt, int regionOff) {
        gload_lds16(src + (size_t)tt * 128 + so0, ldsc + regionOff + c0);
        gload_lds16(src + (size_t)tt * 128 + so1, ldsc + regionOff + c1);
    };

    f32x4 acc[8][4] = {};
    bf16x8 af[4], bf0[4], bf1[4];

    auto RD_A = [&](int bufo, int mh, int kk) {   // 4 x ds_read_b128
        #pragma unroll
        for (int mi = 0; mi < 4; ++mi)
            af[mi] = *(const bf16x8*)(ldsc + bufo + abase + mh * 4096
                            + mi * 1024 + kk * 8192);
    };
    auto RD_B = [&](int bufo, bf16x8 (&bf)[4], int kk) {  // 4 x ds_read_b128
        #pragma unroll
        for (int nb = 0; nb < 4; ++nb)
            bf[nb] = *(const bf16x8*)(ldsc + bufo + bbase + nb * 1024
                            + kk * 8192);
    };
    auto MFQ = [&](bf16x8 (&bf)[4], int mo) {     // 16 MFMA: af x all nb
        #pragma unroll
        for (int mi = 0; mi < 4; ++mi)
            #pragma unroll
            for (int nb = 0; nb < 4; ++nb)
                acc[mo + mi][nb] = __builtin_amdgcn_mfma_f32_16x16x32_bf16(
                    af[mi], bf[nb], acc[mo + mi][nb], 0, 0, 0);
    };

    #define PRIO1 __builtin_amdgcn_s_setprio(1)
    #define PRIO0 __builtin_amdgcn_s_setprio(0)
    #define BARS  do { __builtin_amdgcn_s_barrier(); \
                       __builtin_amdgcn_sched_barrier(0); } while (0)

    // prologue: tile0 full -> buf0; tile1 B halves -> buf1  (12 loads)
    STAGE(srcA0, 0, 0);
    STAGE(srcA1, 0, 16384);
    STAGE(srcB0, 0, 32768);
    STAGE(srcB1, 0, 49152);
    STAGE(srcB0, 1, 65536 + 32768);
    STAGE(srcB1, 1, 65536 + 49152);
    asm volatile("s_waitcnt vmcnt(4)" ::: "memory");   // tile0's 8 landed
    BARS;

    for (int t = 0; t < NT; t += 2) {
        const bool g2 = (t + 2 < NT);

        // ======== tile t (buf0) ========
        // P1: read A(mh0,kk0)+B(kk0) [8]; stage A_lo(t+1)->buf1; MFMA (mh0,kk0)
        RD_A(0, 0, 0); RD_B(0, bf0, 0);
        STAGE(srcA0, t + 1, 65536 + 0);
        BARS;
        PRIO1; MFQ(bf0, 0); PRIO0;

        // P2: read A(mh0,kk1)+B(kk1) [8]; stage A_hi(t+1)->buf1; MFMA (mh0,kk1)
        RD_A(0, 0, 1); RD_B(0, bf1, 1);
        STAGE(srcA1, t + 1, 65536 + 16384);
        BARS;
        PRIO1; MFQ(bf1, 0); PRIO0;

        // P3: read A(mh1,kk0) [4]; stage B_lo(t+2)->buf0; MFMA (mh1,kk0)
        RD_A(0, 1, 0);
        if (g2) STAGE(srcB0, t + 2, 32768);
        BARS;
        PRIO1; MFQ(bf0, 4); PRIO0;

        // P4: read A(mh1,kk1) [4]; stage B_hi(t+2)->buf0; MFMA (mh1,kk1); vmcnt
        RD_A(0, 1, 1);
        if (g2) STAGE(srcB1, t + 2, 49152);
        BARS;
        PRIO1; MFQ(bf1, 4); PRIO0;
        if (g2) { asm volatile("s_waitcnt vmcnt(4)" ::: "memory"); }
        else    { asm volatile("s_waitcnt vmcnt(0)" ::: "memory"); }
        BARS;

        // ======== tile t+1 (buf1) ========
        // P5
        RD_A(65536, 0, 0); RD_B(65536, bf0, 0);
        if (g2) STAGE(srcA0, t + 2, 0);
        BARS;
        PRIO1; MFQ(bf0, 0); PRIO0;

        // P6
        RD_A(65536, 0, 1); RD_B(65536, bf1, 1);
        if (g2) STAGE(srcA1, t + 2, 16384);
        BARS;
        PRIO1; MFQ(bf1, 0); PRIO0;

        // P7
        RD_A(65536, 1, 0);
        if (g2) STAGE(srcB0, t + 3, 65536 + 32768);
        BARS;
        PRIO1; MFQ(bf0, 4); PRIO0;

        // P8
        RD_A(65536, 1, 1);
        if (g2) STAGE(srcB1, t + 3, 65536 + 49152);
        BARS;
        PRIO1; MFQ(bf1, 4); PRIO0;
        if (g2) { asm volatile("s_waitcnt vmcnt(4)" ::: "memory"); }
        BARS;
    }

    #undef PRIO1
    #undef PRIO0
    #undef BARS

    // epilogue: C/D layout col=lane&15, row=(lane>>4)*4+r (round-4 verified)
    float bv[4];
    #pragma unroll
    for (int ni = 0; ni < 4; ++ni)
        bv[ni] = bias[bn * 256 + wc * 64 + ni * 16 + l15];
    #pragma unroll
    for (int mi = 0; mi < 8; ++mi) {
        const int m0 = bm * 256 + wr * 128 + mi * 16 + lk * 4;
        #pragma unroll
        for (int ni = 0; ni < 4; ++ni) {
            const int n = bn * 256 + wc * 64 + ni * 16 + l15;
            #pragma unroll
            for (int r = 0; r < 4; ++r)
                C[(size_t)(m0 + r) * N_DIM + n] = acc[mi][ni][r] + bv[ni];
        }
    }
}

// ---------- fallback (ws too small): slow but correct ----------
__global__ __launch_bounds__(256) void fallback_gemm(
        const float* __restrict__ x, const float* __restrict__ w,
        const float* __restrict__ value, const float* __restrict__ mins,
        const float* __restrict__ maxs, const float* __restrict__ bias,
        float* __restrict__ out) {
    const int n = blockIdx.x;
    __shared__ float wrow[K_DIM];
    const int tid = threadIdx.x;
    if (tid < GROUPS_PER_ROW) {
        const int g = tid;
        const float* wp = w + (size_t)n * K_DIM + g * 32;
        const float* vp = value + (size_t)n * K_DIM + g * 32;
        float tw[32];
        float mn = 1e30f, mx = -1e30f;
        #pragma unroll
        for (int j = 0; j < 32; j++) {
            tw[j] = wp[j]; mn = fminf(mn, tw[j]); mx = fmaxf(mx, tw[j]);
        }
        float wmin = mn * mins[n * GROUPS_PER_ROW + g];
        float wmax = mx * maxs[n * GROUPS_PER_ROW + g];
        float scale = fmaxf((wmax - wmin) * (1.0f / 255.0f), 1e-8f);
        float zp = -wmin / scale;
        #pragma unroll
        for (int j = 0; j < 32; j++) {
            float ws_ = tw[j] / scale + zp + vp[j];
            float q = fminf(fmaxf(rintf(ws_), 0.0f), 255.0f);
            wrow[g * 32 + j] = scale * (q - zp);
        }
    }
    __syncthreads();
    const float bv = bias[n];
    for (int m = tid; m < M_DIM; m += 256) {
        const float4* xr = reinterpret_cast<const float4*>(x + (size_t)m * K_DIM);
        const float4* wr4 = reinterpret_cast<const float4*>(wrow);
        float s = 0.f;
        for (int k = 0; k < K_DIM / 4; k++) {
            float4 a = xr[k], b = wr4[k];
            s += a.x * b.x + a.y * b.y + a.z * b.z + a.w * b.w;
        }
        out[(size_t)m * N_DIM + n] = s + bv;
    }
}

extern "C" void kernel_launch(void* const* d_in, const int* in_sizes, int n_in,
                              void* d_out, int out_size, void* d_ws, size_t ws_size,
                              hipStream_t stream) {
    const float* x     = (const float*)d_in[0];
    const float* ow    = (const float*)d_in[1];
    const float* value = (const float*)d_in[2];
    const float* mins  = (const float*)d_in[3];
    const float* maxs  = (const float*)d_in[4];
    const float* bias  = (const float*)d_in[5];
    float* out = (float*)d_out;

    const size_t xb_bytes = (size_t)M_DIM * K_DIM * 2;
    const size_t wb_bytes = (size_t)N_DIM * K_DIM * 2;

    if (ws_size >= xb_bytes + wb_bytes) {
        unsigned short* xb = (unsigned short*)d_ws;
        unsigned short* wb = (unsigned short*)((char*)d_ws + xb_bytes);

        dequant_kernel<<<(N_DIM * GROUPS_PER_ROW) / 256, 256, 0, stream>>>(
            ow, value, mins, maxs, wb);
        xconv_kernel<<<(M_DIM * K_DIM / 8) / 256, 256, 0, stream>>>(x, xb);
        gemm_kernel<<<(M_DIM / 256) * (N_DIM / 256), 512, 0, stream>>>(
            xb, wb, bias, out);
    } else {
        fallback_gemm<<<N_DIM, 256, 0, stream>>>(x, ow, value, mins, maxs, bias, out);
    }
}